// Round 1
// baseline (4820.004 us; speedup 1.0000x reference)
//
#include <hip/hip_runtime.h>
#include <math.h>

#define BATCH 16384
#define TSTEPS 19
#define INW 17
#define HID 128
#define GATES 512   // 4*HID

#define M 16          // batch rows per workgroup
#define THREADS 256
#define HPAD 132      // HID + 4 pad floats (keeps 16B align, breaks 4-way bank conflict)
#define ZPAD 516      // GATES + 4 pad floats

__device__ __forceinline__ float sigmoidf_(float x) {
    return 1.0f / (1.0f + expf(-x));
}

__global__ __launch_bounds__(THREADS, 2) void flowlstm_kernel(
    const float* __restrict__ x,
    const float* __restrict__ Wih0, const float* __restrict__ Whh0,
    const float* __restrict__ bih0, const float* __restrict__ bhh0,
    const float* __restrict__ Wih1, const float* __restrict__ Whh1,
    const float* __restrict__ bih1, const float* __restrict__ bhh1,
    const float* __restrict__ Wih2, const float* __restrict__ Whh2,
    const float* __restrict__ bih2, const float* __restrict__ bhh2,
    const float* __restrict__ Wl,   const float* __restrict__ bl,
    float* __restrict__ out)
{
    __shared__ float hlds[3][M][HPAD];   // h state per layer
    __shared__ float zbuf[M][ZPAD];      // gate pre-activations
    __shared__ float xs[M][20];          // x tile for this timestep

    const int tid = threadIdx.x;
    const int b0  = blockIdx.x * M;

    // GEMM thread tile: 4 m-groups x 64 n-groups; 4 adjacent lanes share the
    // same n-tile -> weight loads dedupe to 16 distinct lines per instruction.
    const int mg = tid & 3;        // m-group: rows mg*4 .. mg*4+3
    const int ng = tid >> 2;       // n-group: cols ng*8 .. ng*8+7
    const int n0 = ng * 8;

    // Elementwise mapping: thread owns 8 consecutive hidden units of one row.
    const int em  = tid >> 4;             // batch row (0..15)
    const int ej0 = (tid * 8) & (HID-1);  // first hidden unit

    const float* WihA[3] = {Wih0, Wih1, Wih2};
    const float* WhhA[3] = {Whh0, Whh1, Whh2};

    // Hoist bias sums into registers (constant across t).
    float bsum[3][8];
    #pragma unroll
    for (int i = 0; i < 8; ++i) {
        bsum[0][i] = bih0[n0+i] + bhh0[n0+i];
        bsum[1][i] = bih1[n0+i] + bhh1[n0+i];
        bsum[2][i] = bih2[n0+i] + bhh2[n0+i];
    }

    // Zero h state in LDS and c state in registers.
    for (int i = tid; i < 3*M*HPAD; i += THREADS) ((float*)hlds)[i] = 0.0f;
    float cst[3][8];
    #pragma unroll
    for (int l = 0; l < 3; ++l)
        #pragma unroll
        for (int r = 0; r < 8; ++r) cst[l][r] = 0.0f;

    __syncthreads();

    for (int t = 0; t < TSTEPS; ++t) {
        // ---- stage x[:, t, :] into LDS ----
        for (int idx = tid; idx < M*INW; idx += THREADS) {
            int m = idx / INW, i = idx % INW;
            xs[m][i] = x[(size_t)(b0+m)*(TSTEPS*INW) + t*INW + i];
        }
        __syncthreads();

        #pragma unroll 1
        for (int l = 0; l < 3; ++l) {
            const float* __restrict__ Wih = WihA[l];
            const float* __restrict__ Whh = WhhA[l];

            float acc[4][8];
            #pragma unroll
            for (int mi = 0; mi < 4; ++mi)
                #pragma unroll
                for (int i = 0; i < 8; ++i)
                    acc[mi][i] = bsum[l][i];

            // ---- recurrent part: h_l @ Whh^T ----
            #pragma unroll 2
            for (int k0 = 0; k0 < HID; k0 += 4) {
                float4 w[8];
                #pragma unroll
                for (int i = 0; i < 8; ++i)
                    w[i] = *(const float4*)&Whh[(size_t)(n0+i)*HID + k0];
                #pragma unroll
                for (int mi = 0; mi < 4; ++mi) {
                    float4 hv = *(const float4*)&hlds[l][mg*4+mi][k0];
                    #pragma unroll
                    for (int i = 0; i < 8; ++i) {
                        acc[mi][i] = fmaf(hv.x, w[i].x, acc[mi][i]);
                        acc[mi][i] = fmaf(hv.y, w[i].y, acc[mi][i]);
                        acc[mi][i] = fmaf(hv.z, w[i].z, acc[mi][i]);
                        acc[mi][i] = fmaf(hv.w, w[i].w, acc[mi][i]);
                    }
                }
            }

            // ---- input part ----
            if (l == 0) {
                // x is only 17 wide, rows unaligned -> scalar k loop
                #pragma unroll 1
                for (int k = 0; k < INW; ++k) {
                    float wv[8];
                    #pragma unroll
                    for (int i = 0; i < 8; ++i)
                        wv[i] = Wih[(size_t)(n0+i)*INW + k];
                    #pragma unroll
                    for (int mi = 0; mi < 4; ++mi) {
                        float xv = xs[mg*4+mi][k];
                        #pragma unroll
                        for (int i = 0; i < 8; ++i)
                            acc[mi][i] = fmaf(xv, wv[i], acc[mi][i]);
                    }
                }
            } else {
                #pragma unroll 2
                for (int k0 = 0; k0 < HID; k0 += 4) {
                    float4 w[8];
                    #pragma unroll
                    for (int i = 0; i < 8; ++i)
                        w[i] = *(const float4*)&Wih[(size_t)(n0+i)*HID + k0];
                    #pragma unroll
                    for (int mi = 0; mi < 4; ++mi) {
                        float4 hv = *(const float4*)&hlds[l-1][mg*4+mi][k0];
                        #pragma unroll
                        for (int i = 0; i < 8; ++i) {
                            acc[mi][i] = fmaf(hv.x, w[i].x, acc[mi][i]);
                            acc[mi][i] = fmaf(hv.y, w[i].y, acc[mi][i]);
                            acc[mi][i] = fmaf(hv.z, w[i].z, acc[mi][i]);
                            acc[mi][i] = fmaf(hv.w, w[i].w, acc[mi][i]);
                        }
                    }
                }
            }

            // ---- write z tile ----
            #pragma unroll
            for (int mi = 0; mi < 4; ++mi) {
                *(float4*)&zbuf[mg*4+mi][n0] =
                    make_float4(acc[mi][0], acc[mi][1], acc[mi][2], acc[mi][3]);
                *(float4*)&zbuf[mg*4+mi][n0+4] =
                    make_float4(acc[mi][4], acc[mi][5], acc[mi][6], acc[mi][7]);
            }
            __syncthreads();

            // ---- elementwise gate update (PyTorch order i,f,g,o) ----
            #pragma unroll
            for (int r = 0; r < 8; ++r) {
                int j = ej0 + r;
                float zi = zbuf[em][j];
                float zf = zbuf[em][HID   + j];
                float zg = zbuf[em][2*HID + j];
                float zo = zbuf[em][3*HID + j];
                float ig = sigmoidf_(zi);
                float fg = sigmoidf_(zf);
                float og = sigmoidf_(zo);
                float gg = tanhf(zg);
                float cn = fg * cst[l][r] + ig * gg;
                cst[l][r] = cn;
                hlds[l][em][j] = og * tanhf(cn);
            }
            __syncthreads();
        } // layers

        // ---- output projection: out = h2 @ Wl^T + bl ----
        for (int idx = tid; idx < M*INW; idx += THREADS) {
            int m = idx / INW, i = idx % INW;
            float s = bl[i];
            const float* __restrict__ wr = &Wl[(size_t)i*HID];
            const float* __restrict__ hr = &hlds[2][m][0];
            #pragma unroll
            for (int k0 = 0; k0 < HID; k0 += 4) {
                float4 w4 = *(const float4*)&wr[k0];
                float4 h4 = *(const float4*)&hr[k0];
                s = fmaf(h4.x, w4.x, s);
                s = fmaf(h4.y, w4.y, s);
                s = fmaf(h4.z, w4.z, s);
                s = fmaf(h4.w, w4.w, s);
            }
            out[(size_t)(b0+m)*(TSTEPS*INW) + t*INW + i] = s;
        }
        __syncthreads();
    } // t
}

extern "C" void kernel_launch(void* const* d_in, const int* in_sizes, int n_in,
                              void* d_out, int out_size, void* d_ws, size_t ws_size,
                              hipStream_t stream) {
    const float* x    = (const float*)d_in[0];
    const float* Wih0 = (const float*)d_in[1];
    const float* Whh0 = (const float*)d_in[2];
    const float* bih0 = (const float*)d_in[3];
    const float* bhh0 = (const float*)d_in[4];
    const float* Wih1 = (const float*)d_in[5];
    const float* Whh1 = (const float*)d_in[6];
    const float* bih1 = (const float*)d_in[7];
    const float* bhh1 = (const float*)d_in[8];
    const float* Wih2 = (const float*)d_in[9];
    const float* Whh2 = (const float*)d_in[10];
    const float* bih2 = (const float*)d_in[11];
    const float* bhh2 = (const float*)d_in[12];
    const float* Wl   = (const float*)d_in[13];
    const float* bl   = (const float*)d_in[14];
    float* out = (float*)d_out;

    dim3 grid(BATCH / M);
    dim3 block(THREADS);
    flowlstm_kernel<<<grid, block, 0, stream>>>(
        x, Wih0, Whh0, bih0, bhh0, Wih1, Whh1, bih1, bhh1,
        Wih2, Whh2, bih2, bhh2, Wl, bl, out);
}

// Round 2
// 1728.827 us; speedup vs baseline: 2.7880x; 2.7880x over previous
//
#include <hip/hip_runtime.h>
#include <math.h>

#define BATCH  16384
#define TSTEPS 19
#define INW    17
#define HID    128
#define NROW   32          // batch rows per WG
#define THREADS 512        // 8 waves
#define KP     136         // padded row length (halfs) for h state (128+8)
#define KP0    40          // padded row length (halfs) for x (32+8)

typedef _Float16 f16x8 __attribute__((ext_vector_type(8)));
typedef float    f32x4 __attribute__((ext_vector_type(4)));

// ---- ws layout (in halfs) ----
// 5 big matrices [512][128]: Whh0,Whh1,Whh2,Wih1,Wih2
#define W_BIG_HI   0
#define W_BIG_LO   327680          // 5*65536
#define W_IH0_HI   655360          // Wih0 padded [512][32]
#define W_IH0_LO   671744
#define W_HEAD_HI  688128          // Wl padded [32][128]
#define W_HEAD_LO  692224
#define WS_HALFS   696320

__device__ __forceinline__ float fast_rcp(float x) { return __builtin_amdgcn_rcpf(x); }
__device__ __forceinline__ float sigm(float z)  { return fast_rcp(1.0f + __expf(-z)); }
__device__ __forceinline__ float tanh_(float z) { return 1.0f - 2.0f * fast_rcp(1.0f + __expf(2.0f * z)); }

// ---------------- weight conversion: fp32 -> f16 hi/lo ----------------
__global__ void convert_w(const float* __restrict__ Whh0, const float* __restrict__ Whh1,
                          const float* __restrict__ Whh2, const float* __restrict__ Wih1,
                          const float* __restrict__ Wih2, const float* __restrict__ Wih0,
                          const float* __restrict__ Wl, _Float16* __restrict__ ws)
{
    int idx = blockIdx.x * 256 + threadIdx.x;
    if (idx < 327680) {
        int m = idx >> 16, e = idx & 65535;
        const float* src = (m == 0) ? Whh0 : (m == 1) ? Whh1 : (m == 2) ? Whh2
                          : (m == 3) ? Wih1 : Wih2;
        float v = src[e];
        _Float16 hi = (_Float16)v;
        ws[W_BIG_HI + idx] = hi;
        ws[W_BIG_LO + idx] = (_Float16)(v - (float)hi);
    } else if (idx < 344064) {
        int e = idx - 327680;
        int r = e >> 5, k = e & 31;
        float v = (k < INW) ? Wih0[r * INW + k] : 0.0f;
        _Float16 hi = (_Float16)v;
        ws[W_IH0_HI + e] = hi;
        ws[W_IH0_LO + e] = (_Float16)(v - (float)hi);
    } else if (idx < 348160) {
        int e = idx - 344064;
        int r = e >> 7, k = e & 127;
        float v = (r < INW) ? Wl[r * HID + k] : 0.0f;
        _Float16 hi = (_Float16)v;
        ws[W_HEAD_HI + e] = hi;
        ws[W_HEAD_LO + e] = (_Float16)(v - (float)hi);
    }
}

// ---------------- GEMM helpers ----------------
// acc[mt][g] tile: rows m = mt*16 + (lane&15? no: row=(lane>>4)*4+r), cols n = g*128 + wv*16 + (lane&15)
// A from LDS h planes (row-major, stride KP), B from global f16 [512][HID] row-major.
__device__ __forceinline__ void gemm_h(f32x4 acc[2][4],
                                       const _Float16* __restrict__ Ahi,
                                       const _Float16* __restrict__ Alo,
                                       const _Float16* __restrict__ Bhi,
                                       const _Float16* __restrict__ Blo,
                                       int col, int q8, int wv)
{
    const _Float16* a0h = Ahi + col * KP;
    const _Float16* a0l = Alo + col * KP;
    const int nb = wv * 16 + col;
    const _Float16* bh = Bhi + nb * HID + q8;
    const _Float16* bl = Blo + nb * HID + q8;
#pragma unroll
    for (int ks = 0; ks < 4; ++ks) {
        const int ko = ks * 32 + q8;
        f16x8 ah0 = *(const f16x8*)(a0h + ko);
        f16x8 al0 = *(const f16x8*)(a0l + ko);
        f16x8 ah1 = *(const f16x8*)(a0h + 16 * KP + ko);
        f16x8 al1 = *(const f16x8*)(a0l + 16 * KP + ko);
#pragma unroll
        for (int g = 0; g < 4; ++g) {
            f16x8 bhf = *(const f16x8*)(bh + g * (128 * HID) + ks * 32);
            f16x8 blf = *(const f16x8*)(bl + g * (128 * HID) + ks * 32);
            acc[0][g] = __builtin_amdgcn_mfma_f32_16x16x32_f16(ah0, bhf, acc[0][g], 0, 0, 0);
            acc[0][g] = __builtin_amdgcn_mfma_f32_16x16x32_f16(al0, bhf, acc[0][g], 0, 0, 0);
            acc[0][g] = __builtin_amdgcn_mfma_f32_16x16x32_f16(ah0, blf, acc[0][g], 0, 0, 0);
            acc[1][g] = __builtin_amdgcn_mfma_f32_16x16x32_f16(ah1, bhf, acc[1][g], 0, 0, 0);
            acc[1][g] = __builtin_amdgcn_mfma_f32_16x16x32_f16(al1, bhf, acc[1][g], 0, 0, 0);
            acc[1][g] = __builtin_amdgcn_mfma_f32_16x16x32_f16(ah1, blf, acc[1][g], 0, 0, 0);
        }
    }
}

// x-part for layer 0: K=32 (padded), B = Wih0p [512][32]
__device__ __forceinline__ void gemm_x(f32x4 acc[2][4],
                                       const _Float16* __restrict__ Xhi,
                                       const _Float16* __restrict__ Xlo,
                                       const _Float16* __restrict__ Bhi,
                                       const _Float16* __restrict__ Blo,
                                       int col, int q8, int wv)
{
    const int nb = wv * 16 + col;
    const _Float16* bh = Bhi + nb * 32 + q8;
    const _Float16* bl = Blo + nb * 32 + q8;
    f16x8 ah0 = *(const f16x8*)(Xhi + col * KP0 + q8);
    f16x8 al0 = *(const f16x8*)(Xlo + col * KP0 + q8);
    f16x8 ah1 = *(const f16x8*)(Xhi + (16 + col) * KP0 + q8);
    f16x8 al1 = *(const f16x8*)(Xlo + (16 + col) * KP0 + q8);
#pragma unroll
    for (int g = 0; g < 4; ++g) {
        f16x8 bhf = *(const f16x8*)(bh + g * (128 * 32));
        f16x8 blf = *(const f16x8*)(bl + g * (128 * 32));
        acc[0][g] = __builtin_amdgcn_mfma_f32_16x16x32_f16(ah0, bhf, acc[0][g], 0, 0, 0);
        acc[0][g] = __builtin_amdgcn_mfma_f32_16x16x32_f16(al0, bhf, acc[0][g], 0, 0, 0);
        acc[0][g] = __builtin_amdgcn_mfma_f32_16x16x32_f16(ah0, blf, acc[0][g], 0, 0, 0);
        acc[1][g] = __builtin_amdgcn_mfma_f32_16x16x32_f16(ah1, bhf, acc[1][g], 0, 0, 0);
        acc[1][g] = __builtin_amdgcn_mfma_f32_16x16x32_f16(al1, bhf, acc[1][g], 0, 0, 0);
        acc[1][g] = __builtin_amdgcn_mfma_f32_16x16x32_f16(ah1, blf, acc[1][g], 0, 0, 0);
    }
}

// ---------------- main kernel ----------------
__global__ __launch_bounds__(THREADS, 4) void lstm_mfma(
    const float* __restrict__ x,
    const float* __restrict__ bih0, const float* __restrict__ bhh0,
    const float* __restrict__ bih1, const float* __restrict__ bhh1,
    const float* __restrict__ bih2, const float* __restrict__ bhh2,
    const float* __restrict__ bl,
    const _Float16* __restrict__ wsp,
    float* __restrict__ out)
{
    __shared__ _Float16 Hs[2][3][NROW][KP];   // [hi/lo][layer][m][k]
    __shared__ _Float16 Xs[2][NROW][KP0];     // [hi/lo][m][k]
    __shared__ float    Bs[3][512];           // bih+bhh per layer

    const int tid  = threadIdx.x;
    const int wv   = tid >> 6;
    const int lane = tid & 63;
    const int col  = lane & 15;
    const int quad = lane >> 4;
    const int q8   = quad * 8;
    const int b0   = blockIdx.x * NROW;

    // stage bias sums
    for (int i = tid; i < 1536; i += THREADS) {
        int l = i >> 9, n = i & 511;
        const float* bi = (l == 0) ? bih0 : (l == 1) ? bih1 : bih2;
        const float* bh = (l == 0) ? bhh0 : (l == 1) ? bhh1 : bhh2;
        Bs[l][n] = bi[n] + bh[n];
    }
    // zero h state (hi+lo planes): 2*3*32*136 halfs = 13056 floats
    for (int i = tid; i < 13056; i += THREADS) ((float*)Hs)[i] = 0.0f;

    f32x4 cst[3][2];
#pragma unroll
    for (int l = 0; l < 3; ++l) { cst[l][0] = (f32x4){0,0,0,0}; cst[l][1] = (f32x4){0,0,0,0}; }

    // weight pointers
    const _Float16* WhhHi[3] = {wsp + W_BIG_HI,           wsp + W_BIG_HI + 65536,  wsp + W_BIG_HI + 131072};
    const _Float16* WhhLo[3] = {wsp + W_BIG_LO,           wsp + W_BIG_LO + 65536,  wsp + W_BIG_LO + 131072};
    const _Float16* WihHi[3] = {wsp + W_IH0_HI,           wsp + W_BIG_HI + 196608, wsp + W_BIG_HI + 262144};
    const _Float16* WihLo[3] = {wsp + W_IH0_LO,           wsp + W_BIG_LO + 196608, wsp + W_BIG_LO + 262144};

    // head bias (waves 0..3 only)
    float blv = 0.0f;
    {
        int i = (wv & 1) * 16 + col;
        if (wv < 4 && i < INW) blv = bl[i];
    }

    __syncthreads();

    for (int t = 0; t < TSTEPS; ++t) {
        // ---- stage x[:, t, :] as f16 hi/lo (K padded to 32) ----
        for (int ii = tid; ii < NROW * 32; ii += THREADS) {
            int m = ii >> 5, k = ii & 31;
            float v = (k < INW) ? x[(size_t)(b0 + m) * (TSTEPS * INW) + t * INW + k] : 0.0f;
            _Float16 hi = (_Float16)v;
            Xs[0][m][k] = hi;
            Xs[1][m][k] = (_Float16)(v - (float)hi);
        }
        __syncthreads();

#pragma unroll 1
        for (int l = 0; l < 3; ++l) {
            f32x4 acc[2][4];
#pragma unroll
            for (int mt = 0; mt < 2; ++mt)
#pragma unroll
                for (int g = 0; g < 4; ++g) {
                    float bv = Bs[l][g * 128 + wv * 16 + col];
                    acc[mt][g] = (f32x4){bv, bv, bv, bv};
                }

            // input contribution
            if (l == 0)
                gemm_x(acc, &Xs[0][0][0], &Xs[1][0][0], WihHi[0], WihLo[0], col, q8, wv);
            else
                gemm_h(acc, &Hs[0][l - 1][0][0], &Hs[1][l - 1][0][0], WihHi[l], WihLo[l], col, q8, wv);
            // recurrent contribution
            gemm_h(acc, &Hs[0][l][0][0], &Hs[1][l][0][0], WhhHi[l], WhhLo[l], col, q8, wv);

            __syncthreads();   // all reads of Hs[l] (and Hs[l-1]) complete

            // gates fully in-register; write new h (hi/lo) to LDS
#pragma unroll
            for (int mt = 0; mt < 2; ++mt) {
#pragma unroll
                for (int r = 0; r < 4; ++r) {
                    float zi = acc[mt][0][r];
                    float zf = acc[mt][1][r];
                    float zg = acc[mt][2][r];
                    float zo = acc[mt][3][r];
                    float ig = sigm(zi), fg = sigm(zf), og = sigm(zo), gg = tanh_(zg);
                    float cn = fg * cst[l][mt][r] + ig * gg;
                    cst[l][mt][r] = cn;
                    float h = og * tanh_(cn);
                    int m = mt * 16 + quad * 4 + r;
                    int j = wv * 16 + col;
                    _Float16 hh = (_Float16)h;
                    Hs[0][l][m][j] = hh;
                    Hs[1][l][m][j] = (_Float16)(h - (float)hh);
                }
            }
            __syncthreads();   // new h visible
        }

        // ---- head: out = h2 @ Wl^T + bl  (waves 0..3: mt = wv>>1, nt = wv&1) ----
        if (wv < 4) {
            const int mt = wv >> 1, nt = wv & 1;
            const _Float16* ah = &Hs[0][2][mt * 16 + col][0];
            const _Float16* al = &Hs[1][2][mt * 16 + col][0];
            const _Float16* bh = wsp + W_HEAD_HI + (nt * 16 + col) * HID + q8;
            const _Float16* bl_ = wsp + W_HEAD_LO + (nt * 16 + col) * HID + q8;
            f32x4 o = (f32x4){0, 0, 0, 0};
#pragma unroll
            for (int ks = 0; ks < 4; ++ks) {
                f16x8 a_h = *(const f16x8*)(ah + ks * 32 + q8);
                f16x8 a_l = *(const f16x8*)(al + ks * 32 + q8);
                f16x8 b_h = *(const f16x8*)(bh + ks * 32);
                f16x8 b_l = *(const f16x8*)(bl_ + ks * 32);
                o = __builtin_amdgcn_mfma_f32_16x16x32_f16(a_h, b_h, o, 0, 0, 0);
                o = __builtin_amdgcn_mfma_f32_16x16x32_f16(a_l, b_h, o, 0, 0, 0);
                o = __builtin_amdgcn_mfma_f32_16x16x32_f16(a_h, b_l, o, 0, 0, 0);
            }
            int i = nt * 16 + col;
            if (i < INW) {
#pragma unroll
                for (int r = 0; r < 4; ++r) {
                    int m = mt * 16 + quad * 4 + r;
                    out[(size_t)(b0 + m) * (TSTEPS * INW) + t * INW + i] = o[r] + blv;
                }
            }
        }
        __syncthreads();   // head reads of Hs[2] + Xs reuse fence before next t
    }
}

extern "C" void kernel_launch(void* const* d_in, const int* in_sizes, int n_in,
                              void* d_out, int out_size, void* d_ws, size_t ws_size,
                              hipStream_t stream) {
    const float* x    = (const float*)d_in[0];
    const float* Wih0 = (const float*)d_in[1];
    const float* Whh0 = (const float*)d_in[2];
    const float* bih0 = (const float*)d_in[3];
    const float* bhh0 = (const float*)d_in[4];
    const float* Wih1 = (const float*)d_in[5];
    const float* Whh1 = (const float*)d_in[6];
    const float* bih1 = (const float*)d_in[7];
    const float* bhh1 = (const float*)d_in[8];
    const float* Wih2 = (const float*)d_in[9];
    const float* Whh2 = (const float*)d_in[10];
    const float* bih2 = (const float*)d_in[11];
    const float* bhh2 = (const float*)d_in[12];
    const float* Wl   = (const float*)d_in[13];
    const float* bl   = (const float*)d_in[14];
    float* out = (float*)d_out;
    _Float16* ws = (_Float16*)d_ws;

    convert_w<<<(348160 + 255) / 256, 256, 0, stream>>>(Whh0, Whh1, Whh2, Wih1, Wih2, Wih0, Wl, ws);
    lstm_mfma<<<BATCH / NROW, THREADS, 0, stream>>>(
        x, bih0, bhh0, bih1, bhh1, bih2, bhh2, bl, ws, out);
}

// Round 3
// 1706.773 us; speedup vs baseline: 2.8240x; 1.0129x over previous
//
#include <hip/hip_runtime.h>
#include <math.h>

#define BATCH  16384
#define TSTEPS 19
#define INW    17
#define HID    128
#define NROW   32          // batch rows per WG
#define THREADS 512        // 8 waves
#define KP     136         // padded row length (halfs) for h state (128+8)
#define KP0    40          // padded row length (halfs) for x (32+8)

typedef _Float16 f16x8 __attribute__((ext_vector_type(8)));
typedef float    f32x4 __attribute__((ext_vector_type(4)));

// ---- ws layout (in halfs), hi/lo interleaved per row ----
// 5 big matrices [512 rows][256: hi(128)|lo(128)]: Whh0,Whh1,Whh2,Wih1,Wih2
#define W_BIG      0                 // 5*512*256 = 655360
#define W_IH0      655360            // [512][64: hi32|lo32] = 32768
#define W_HEAD     688128            // [32][256: hi128|lo128] = 8192
#define WS_HALFS   696320

__device__ __forceinline__ float fast_rcp(float x) { return __builtin_amdgcn_rcpf(x); }
__device__ __forceinline__ float sigm(float z)  { return fast_rcp(1.0f + __expf(-z)); }
__device__ __forceinline__ float tanh_(float z) { return 1.0f - 2.0f * fast_rcp(1.0f + __expf(2.0f * z)); }

// ---------------- weight conversion: fp32 -> f16 hi/lo (interleaved rows) ----------------
__global__ void convert_w(const float* __restrict__ Whh0, const float* __restrict__ Whh1,
                          const float* __restrict__ Whh2, const float* __restrict__ Wih1,
                          const float* __restrict__ Wih2, const float* __restrict__ Wih0,
                          const float* __restrict__ Wl, _Float16* __restrict__ ws)
{
    int idx = blockIdx.x * 256 + threadIdx.x;
    if (idx < 327680) {
        int m = idx >> 16, e = idx & 65535;
        int r = e >> 7, k = e & 127;
        const float* src = (m == 0) ? Whh0 : (m == 1) ? Whh1 : (m == 2) ? Whh2
                          : (m == 3) ? Wih1 : Wih2;
        float v = src[e];
        _Float16 hi = (_Float16)v;
        int dst = W_BIG + m * 131072 + r * 256 + k;
        ws[dst]       = hi;
        ws[dst + 128] = (_Float16)(v - (float)hi);
    } else if (idx < 344064) {
        int e = idx - 327680;              // [0, 16384)
        int r = e >> 5, k = e & 31;
        float v = (k < INW) ? Wih0[r * INW + k] : 0.0f;
        _Float16 hi = (_Float16)v;
        int dst = W_IH0 + r * 64 + k;
        ws[dst]      = hi;
        ws[dst + 32] = (_Float16)(v - (float)hi);
    } else if (idx < 348160) {
        int e = idx - 344064;              // [0, 4096)
        int r = e >> 7, k = e & 127;
        float v = (r < INW) ? Wl[(size_t)r * HID + k] : 0.0f;
        _Float16 hi = (_Float16)v;
        int dst = W_HEAD + r * 256 + k;
        ws[dst]       = hi;
        ws[dst + 128] = (_Float16)(v - (float)hi);
    }
}

// ---------------- GEMM helpers ----------------
// acc[mt][g]: rows m = mt*16 + quad*4 + r, cols n = g*128 + wv*16 + col
// A from LDS h planes (hi/lo, row-major stride KP), B rows = [hi128|lo128] in ws.
__device__ __forceinline__ void gemm_h(f32x4 acc[2][4],
                                       const _Float16* __restrict__ Ahi,
                                       const _Float16* __restrict__ Alo,
                                       const _Float16* __restrict__ B,
                                       int col, int q8, int wv)
{
    const _Float16* a0h = Ahi + col * KP;
    const _Float16* a0l = Alo + col * KP;
    const _Float16* b0  = B + (wv * 16 + col) * 256 + q8;   // hi at +ks*32, lo at +128
#pragma unroll
    for (int ks = 0; ks < 4; ++ks) {
        const int ko = ks * 32 + q8;
        f16x8 ah0 = *(const f16x8*)(a0h + ko);
        f16x8 al0 = *(const f16x8*)(a0l + ko);
        f16x8 ah1 = *(const f16x8*)(a0h + 16 * KP + ko);
        f16x8 al1 = *(const f16x8*)(a0l + 16 * KP + ko);
#pragma unroll
        for (int g = 0; g < 4; ++g) {
            const _Float16* bg = b0 + g * (128 * 256) + ks * 32;
            f16x8 bhf = *(const f16x8*)(bg);
            f16x8 blf = *(const f16x8*)(bg + 128);
            acc[0][g] = __builtin_amdgcn_mfma_f32_16x16x32_f16(ah0, bhf, acc[0][g], 0, 0, 0);
            acc[0][g] = __builtin_amdgcn_mfma_f32_16x16x32_f16(al0, bhf, acc[0][g], 0, 0, 0);
            acc[0][g] = __builtin_amdgcn_mfma_f32_16x16x32_f16(ah0, blf, acc[0][g], 0, 0, 0);
            acc[1][g] = __builtin_amdgcn_mfma_f32_16x16x32_f16(ah1, bhf, acc[1][g], 0, 0, 0);
            acc[1][g] = __builtin_amdgcn_mfma_f32_16x16x32_f16(al1, bhf, acc[1][g], 0, 0, 0);
            acc[1][g] = __builtin_amdgcn_mfma_f32_16x16x32_f16(ah1, blf, acc[1][g], 0, 0, 0);
        }
    }
}

// x-part for layer 0: K=32 (padded), B rows = [hi32|lo32]
__device__ __forceinline__ void gemm_x(f32x4 acc[2][4],
                                       const _Float16* __restrict__ Xhi,
                                       const _Float16* __restrict__ Xlo,
                                       const _Float16* __restrict__ B,
                                       int col, int q8, int wv)
{
    const _Float16* b0 = B + (wv * 16 + col) * 64 + q8;
    f16x8 ah0 = *(const f16x8*)(Xhi + col * KP0 + q8);
    f16x8 al0 = *(const f16x8*)(Xlo + col * KP0 + q8);
    f16x8 ah1 = *(const f16x8*)(Xhi + (16 + col) * KP0 + q8);
    f16x8 al1 = *(const f16x8*)(Xlo + (16 + col) * KP0 + q8);
#pragma unroll
    for (int g = 0; g < 4; ++g) {
        const _Float16* bg = b0 + g * (128 * 64);
        f16x8 bhf = *(const f16x8*)(bg);
        f16x8 blf = *(const f16x8*)(bg + 32);
        acc[0][g] = __builtin_amdgcn_mfma_f32_16x16x32_f16(ah0, bhf, acc[0][g], 0, 0, 0);
        acc[0][g] = __builtin_amdgcn_mfma_f32_16x16x32_f16(al0, bhf, acc[0][g], 0, 0, 0);
        acc[0][g] = __builtin_amdgcn_mfma_f32_16x16x32_f16(ah0, blf, acc[0][g], 0, 0, 0);
        acc[1][g] = __builtin_amdgcn_mfma_f32_16x16x32_f16(ah1, bhf, acc[1][g], 0, 0, 0);
        acc[1][g] = __builtin_amdgcn_mfma_f32_16x16x32_f16(al1, bhf, acc[1][g], 0, 0, 0);
        acc[1][g] = __builtin_amdgcn_mfma_f32_16x16x32_f16(ah1, blf, acc[1][g], 0, 0, 0);
    }
}

// ---------------- main kernel ----------------
__global__ __launch_bounds__(THREADS, 2) void lstm_mfma(
    const float* __restrict__ x,
    const float* __restrict__ bih0, const float* __restrict__ bhh0,
    const float* __restrict__ bih1, const float* __restrict__ bhh1,
    const float* __restrict__ bih2, const float* __restrict__ bhh2,
    const float* __restrict__ bl,
    const _Float16* __restrict__ wsp,
    float* __restrict__ out)
{
    __shared__ _Float16 Hs[2][3][NROW][KP];   // [hi/lo][layer][m][k]
    __shared__ _Float16 Xs[2][NROW][KP0];     // [hi/lo][m][k]
    __shared__ float    Bs[3][512];           // bih+bhh per layer

    const int tid  = threadIdx.x;
    const int wv   = tid >> 6;
    const int lane = tid & 63;
    const int col  = lane & 15;
    const int quad = lane >> 4;
    const int q8   = quad * 8;
    const int b0   = blockIdx.x * NROW;

    // stage bias sums
    for (int i = tid; i < 1536; i += THREADS) {
        int l = i >> 9, n = i & 511;
        const float* bi = (l == 0) ? bih0 : (l == 1) ? bih1 : bih2;
        const float* bh = (l == 0) ? bhh0 : (l == 1) ? bhh1 : bhh2;
        Bs[l][n] = bi[n] + bh[n];
    }
    // zero h state (hi+lo planes): 2*3*32*136 halfs = 13056 floats
    for (int i = tid; i < 13056; i += THREADS) ((float*)Hs)[i] = 0.0f;

    f32x4 cst[3][2];
#pragma unroll
    for (int l = 0; l < 3; ++l) { cst[l][0] = (f32x4){0,0,0,0}; cst[l][1] = (f32x4){0,0,0,0}; }

    // weight pointers (hi/lo interleaved rows)
    const _Float16* Whh[3] = {wsp + W_BIG,          wsp + W_BIG + 131072, wsp + W_BIG + 262144};
    const _Float16* Wih[3] = {wsp + W_IH0,          wsp + W_BIG + 393216, wsp + W_BIG + 524288};

    // head bias (waves 0..3 only)
    float blv = 0.0f;
    {
        int i = (wv & 1) * 16 + col;
        if (wv < 4 && i < INW) blv = bl[i];
    }

    __syncthreads();

    for (int t = 0; t < TSTEPS; ++t) {
        // ---- stage x[:, t, :] as f16 hi/lo (K padded to 32) ----
        for (int ii = tid; ii < NROW * 32; ii += THREADS) {
            int m = ii >> 5, k = ii & 31;
            float v = (k < INW) ? x[(size_t)(b0 + m) * (TSTEPS * INW) + t * INW + k] : 0.0f;
            _Float16 hi = (_Float16)v;
            Xs[0][m][k] = hi;
            Xs[1][m][k] = (_Float16)(v - (float)hi);
        }
        __syncthreads();

#pragma unroll 1
        for (int l = 0; l < 3; ++l) {
            f32x4 acc[2][4];
#pragma unroll
            for (int mt = 0; mt < 2; ++mt)
#pragma unroll
                for (int g = 0; g < 4; ++g) {
                    float bv = Bs[l][g * 128 + wv * 16 + col];
                    acc[mt][g] = (f32x4){bv, bv, bv, bv};
                }

            // input contribution
            if (l == 0)
                gemm_x(acc, &Xs[0][0][0], &Xs[1][0][0], Wih[0], col, q8, wv);
            else
                gemm_h(acc, &Hs[0][l - 1][0][0], &Hs[1][l - 1][0][0], Wih[l], col, q8, wv);
            // recurrent contribution
            gemm_h(acc, &Hs[0][l][0][0], &Hs[1][l][0][0], Whh[l], col, q8, wv);

            __syncthreads();   // all reads of Hs[l] (and Hs[l-1]) complete

            // gates fully in-register; write new h (hi/lo) to LDS
#pragma unroll
            for (int mt = 0; mt < 2; ++mt) {
#pragma unroll
                for (int r = 0; r < 4; ++r) {
                    float zi = acc[mt][0][r];
                    float zf = acc[mt][1][r];
                    float zg = acc[mt][2][r];
                    float zo = acc[mt][3][r];
                    float ig = sigm(zi), fg = sigm(zf), og = sigm(zo), gg = tanh_(zg);
                    float cn = fg * cst[l][mt][r] + ig * gg;
                    cst[l][mt][r] = cn;
                    float h = og * tanh_(cn);
                    int m = mt * 16 + quad * 4 + r;
                    int j = wv * 16 + col;
                    _Float16 hh = (_Float16)h;
                    Hs[0][l][m][j] = hh;
                    Hs[1][l][m][j] = (_Float16)(h - (float)hh);
                }
            }
            __syncthreads();   // new h visible
        }

        // ---- head: out = h2 @ Wl^T + bl  (waves 0..3: mt = wv>>1, nt = wv&1) ----
        if (wv < 4) {
            const int mt = wv >> 1, nt = wv & 1;
            const _Float16* ah = &Hs[0][2][mt * 16 + col][0];
            const _Float16* al = &Hs[1][2][mt * 16 + col][0];
            const _Float16* bb = wsp + W_HEAD + (nt * 16 + col) * 256 + q8;
            f32x4 o = (f32x4){0, 0, 0, 0};
#pragma unroll
            for (int ks = 0; ks < 4; ++ks) {
                f16x8 a_h = *(const f16x8*)(ah + ks * 32 + q8);
                f16x8 a_l = *(const f16x8*)(al + ks * 32 + q8);
                f16x8 b_h = *(const f16x8*)(bb + ks * 32);
                f16x8 b_l = *(const f16x8*)(bb + ks * 32 + 128);
                o = __builtin_amdgcn_mfma_f32_16x16x32_f16(a_h, b_h, o, 0, 0, 0);
                o = __builtin_amdgcn_mfma_f32_16x16x32_f16(a_l, b_h, o, 0, 0, 0);
                o = __builtin_amdgcn_mfma_f32_16x16x32_f16(a_h, b_l, o, 0, 0, 0);
            }
            int i = nt * 16 + col;
            if (i < INW) {
#pragma unroll
                for (int r = 0; r < 4; ++r) {
                    int m = mt * 16 + quad * 4 + r;
                    out[(size_t)(b0 + m) * (TSTEPS * INW) + t * INW + i] = o[r] + blv;
                }
            }
        }
        __syncthreads();   // head reads of Hs[2] + Xs reuse fence before next t
    }
}

extern "C" void kernel_launch(void* const* d_in, const int* in_sizes, int n_in,
                              void* d_out, int out_size, void* d_ws, size_t ws_size,
                              hipStream_t stream) {
    const float* x    = (const float*)d_in[0];
    const float* Wih0 = (const float*)d_in[1];
    const float* Whh0 = (const float*)d_in[2];
    const float* bih0 = (const float*)d_in[3];
    const float* bhh0 = (const float*)d_in[4];
    const float* Wih1 = (const float*)d_in[5];
    const float* Whh1 = (const float*)d_in[6];
    const float* bih1 = (const float*)d_in[7];
    const float* bhh1 = (const float*)d_in[8];
    const float* Wih2 = (const float*)d_in[9];
    const float* Whh2 = (const float*)d_in[10];
    const float* bih2 = (const float*)d_in[11];
    const float* bhh2 = (const float*)d_in[12];
    const float* Wl   = (const float*)d_in[13];
    const float* bl   = (const float*)d_in[14];
    float* out = (float*)d_out;
    _Float16* ws = (_Float16*)d_ws;

    convert_w<<<(348160 + 255) / 256, 256, 0, stream>>>(Whh0, Whh1, Whh2, Wih1, Wih2, Wih0, Wl, ws);
    lstm_mfma<<<BATCH / NROW, THREADS, 0, stream>>>(
        x, bih0, bhh0, bih1, bhh1, bih2, bhh2, bl, ws, out);
}

// Round 4
// 911.383 us; speedup vs baseline: 5.2887x; 1.8727x over previous
//
#include <hip/hip_runtime.h>
#include <math.h>

#define BATCH  16384
#define TSTEPS 19
#define INW    17
#define HID    128
#define NROW   64          // batch rows per WG -> grid = 256 = 1 block/CU
#define THREADS 512        // 8 waves
#define KP     136         // padded row length (halfs) for h state (128+8)
#define KP0    40          // padded row length (halfs) for x (32+8)

typedef _Float16 f16x8 __attribute__((ext_vector_type(8)));
typedef float    f32x4 __attribute__((ext_vector_type(4)));

// ---- ws layout (halfs), MFMA-fragment-ordered tiles ----
// Big matrices (Whh0,Whh1,Whh2,Wih1,Wih2), each [512 rows][128 k]:
//   tile (n_tile 0..31, ks 0..3) = 1024 halfs: hi[512] | lo[512],
//   within plane: (quad*16 + col)*8 + j  -> lane*8 is coalesced.
#define W_BIG      0                 // 5 * 131072 = 655360
#define W_IH0      655360            // [512][32]: tile n_tile 0..31 = 1024 halfs (hi512|lo512)
#define W_HEAD     688128            // [32 rows][128]: (n_tile 0..1, ks 0..3) tiles of 1024
#define WS_HALFS   696320

__device__ __forceinline__ float fast_rcp(float x) { return __builtin_amdgcn_rcpf(x); }
__device__ __forceinline__ float sigm(float z)  { return fast_rcp(1.0f + __expf(-z)); }
__device__ __forceinline__ float tanh_(float z) { return 1.0f - 2.0f * fast_rcp(1.0f + __expf(2.0f * z)); }

// ---------------- weight conversion: fp32 -> f16 hi/lo, fragment order ----------------
__global__ void convert_w(const float* __restrict__ Whh0, const float* __restrict__ Whh1,
                          const float* __restrict__ Whh2, const float* __restrict__ Wih1,
                          const float* __restrict__ Wih2, const float* __restrict__ Wih0,
                          const float* __restrict__ Wl, _Float16* __restrict__ ws)
{
    int idx = blockIdx.x * 256 + threadIdx.x;
    if (idx < 327680) {
        int m = idx >> 16, e = idx & 65535;
        int r = e >> 7, k = e & 127;
        const float* src = (m == 0) ? Whh0 : (m == 1) ? Whh1 : (m == 2) ? Whh2
                          : (m == 3) ? Wih1 : Wih2;
        float v = src[e];
        _Float16 hi = (_Float16)v;
        int n_tile = r >> 4, colr = r & 15, ks = k >> 5, qd = (k >> 3) & 3, j = k & 7;
        int dst = W_BIG + m * 131072 + (n_tile * 4 + ks) * 1024 + (qd * 16 + colr) * 8 + j;
        ws[dst]       = hi;
        ws[dst + 512] = (_Float16)(v - (float)hi);
    } else if (idx < 344064) {
        int e = idx - 327680;              // [0, 16384)
        int r = e >> 5, k = e & 31;
        float v = (k < INW) ? Wih0[r * INW + k] : 0.0f;
        _Float16 hi = (_Float16)v;
        int n_tile = r >> 4, colr = r & 15, qd = k >> 3, j = k & 7;
        int dst = W_IH0 + n_tile * 1024 + (qd * 16 + colr) * 8 + j;
        ws[dst]       = hi;
        ws[dst + 512] = (_Float16)(v - (float)hi);
    } else if (idx < 348160) {
        int e = idx - 344064;              // [0, 4096)
        int r = e >> 7, k = e & 127;
        float v = (r < INW) ? Wl[(size_t)r * HID + k] : 0.0f;
        _Float16 hi = (_Float16)v;
        int n_tile = r >> 4, colr = r & 15, ks = k >> 5, qd = (k >> 3) & 3, j = k & 7;
        int dst = W_HEAD + (n_tile * 4 + ks) * 1024 + (qd * 16 + colr) * 8 + j;
        ws[dst]       = hi;
        ws[dst + 512] = (_Float16)(v - (float)hi);
    }
}

// ---------------- GEMM helpers ----------------
// acc[mt][g]: rows m = mt*16 + quad*4 + r, cols n = g*128 + wv*16 + col
// A from LDS h planes (hi/lo, row-major stride KP).
// B fragment tiles: coalesced, lane*8 offset within 512-half plane.
__device__ __forceinline__ void gemm_h(f32x4 acc[4][4],
                                       const _Float16* __restrict__ Ahi,
                                       const _Float16* __restrict__ Alo,
                                       const _Float16* __restrict__ B,
                                       int col, int q8, int wv, int lane)
{
    const _Float16* a_h = Ahi + col * KP;
    const _Float16* a_l = Alo + col * KP;
    const int l8 = lane * 8;
#pragma unroll
    for (int ks = 0; ks < 4; ++ks) {
        const int ko = ks * 32 + q8;
        f16x8 ah[4], al[4];
#pragma unroll
        for (int mt = 0; mt < 4; ++mt) {
            ah[mt] = *(const f16x8*)(a_h + mt * 16 * KP + ko);
            al[mt] = *(const f16x8*)(a_l + mt * 16 * KP + ko);
        }
#pragma unroll
        for (int g = 0; g < 4; ++g) {
            const _Float16* bt = B + ((g * 8 + wv) * 4 + ks) * 1024 + l8;
            f16x8 bh  = *(const f16x8*)(bt);
            f16x8 blo = *(const f16x8*)(bt + 512);
#pragma unroll
            for (int mt = 0; mt < 4; ++mt) {
                acc[mt][g] = __builtin_amdgcn_mfma_f32_16x16x32_f16(ah[mt], bh,  acc[mt][g], 0, 0, 0);
                acc[mt][g] = __builtin_amdgcn_mfma_f32_16x16x32_f16(al[mt], bh,  acc[mt][g], 0, 0, 0);
                acc[mt][g] = __builtin_amdgcn_mfma_f32_16x16x32_f16(ah[mt], blo, acc[mt][g], 0, 0, 0);
            }
        }
    }
}

// x-part for layer 0: K=32 (padded)
__device__ __forceinline__ void gemm_x(f32x4 acc[4][4],
                                       const _Float16* __restrict__ Xhi,
                                       const _Float16* __restrict__ Xlo,
                                       const _Float16* __restrict__ B,
                                       int col, int q8, int wv, int lane)
{
    const int l8 = lane * 8;
    f16x8 ah[4], al[4];
#pragma unroll
    for (int mt = 0; mt < 4; ++mt) {
        ah[mt] = *(const f16x8*)(Xhi + (mt * 16 + col) * KP0 + q8);
        al[mt] = *(const f16x8*)(Xlo + (mt * 16 + col) * KP0 + q8);
    }
#pragma unroll
    for (int g = 0; g < 4; ++g) {
        const _Float16* bt = B + (g * 8 + wv) * 1024 + l8;
        f16x8 bh  = *(const f16x8*)(bt);
        f16x8 blo = *(const f16x8*)(bt + 512);
#pragma unroll
        for (int mt = 0; mt < 4; ++mt) {
            acc[mt][g] = __builtin_amdgcn_mfma_f32_16x16x32_f16(ah[mt], bh,  acc[mt][g], 0, 0, 0);
            acc[mt][g] = __builtin_amdgcn_mfma_f32_16x16x32_f16(al[mt], bh,  acc[mt][g], 0, 0, 0);
            acc[mt][g] = __builtin_amdgcn_mfma_f32_16x16x32_f16(ah[mt], blo, acc[mt][g], 0, 0, 0);
        }
    }
}

// ---------------- main kernel ----------------
__global__ __launch_bounds__(THREADS, 2) void lstm_mfma(
    const float* __restrict__ x,
    const float* __restrict__ bih0, const float* __restrict__ bhh0,
    const float* __restrict__ bih1, const float* __restrict__ bhh1,
    const float* __restrict__ bih2, const float* __restrict__ bhh2,
    const float* __restrict__ bl,
    const _Float16* __restrict__ wsp,
    float* __restrict__ out)
{
    __shared__ _Float16 Hs[2][3][NROW][KP];   // [hi/lo][layer][m][k]  = 104448 B
    __shared__ _Float16 Xs[2][NROW][KP0];     // [hi/lo][m][k]         = 10240 B

    const int tid  = threadIdx.x;
    const int wv   = tid >> 6;
    const int lane = tid & 63;
    const int col  = lane & 15;
    const int quad = lane >> 4;
    const int q8   = quad * 8;
    const int b0   = blockIdx.x * NROW;

    // bias sums in registers: bsum[l][g] for n = g*128 + wv*16 + col
    const float* bihA[3] = {bih0, bih1, bih2};
    const float* bhhA[3] = {bhh0, bhh1, bhh2};
    float bsum[3][4];
#pragma unroll
    for (int l = 0; l < 3; ++l)
#pragma unroll
        for (int g = 0; g < 4; ++g) {
            int n = g * 128 + wv * 16 + col;
            bsum[l][g] = bihA[l][n] + bhhA[l][n];
        }

    // zero h state (hi+lo planes): 104448 B = 26112 floats
    for (int i = tid; i < 26112; i += THREADS) ((float*)Hs)[i] = 0.0f;

    f32x4 cst[3][4];
#pragma unroll
    for (int l = 0; l < 3; ++l)
#pragma unroll
        for (int mt = 0; mt < 4; ++mt) cst[l][mt] = (f32x4){0, 0, 0, 0};

    // weight pointers (fragment-ordered)
    const _Float16* Whh[3] = {wsp + W_BIG,  wsp + W_BIG + 131072, wsp + W_BIG + 262144};
    const _Float16* Wih[3] = {wsp + W_IH0, wsp + W_BIG + 393216, wsp + W_BIG + 524288};

    // head bias
    float blv = 0.0f;
    {
        int i = (wv & 1) * 16 + col;
        if (i < INW) blv = bl[i];
    }

    __syncthreads();

    for (int t = 0; t < TSTEPS; ++t) {
        // ---- stage x[:, t, :] as f16 hi/lo (K padded to 32) ----
        for (int ii = tid; ii < NROW * 32; ii += THREADS) {
            int m = ii >> 5, k = ii & 31;
            float v = (k < INW) ? x[(size_t)(b0 + m) * (TSTEPS * INW) + t * INW + k] : 0.0f;
            _Float16 hi = (_Float16)v;
            Xs[0][m][k] = hi;
            Xs[1][m][k] = (_Float16)(v - (float)hi);
        }
        __syncthreads();

#pragma unroll 1
        for (int l = 0; l < 3; ++l) {
            f32x4 acc[4][4];
#pragma unroll
            for (int mt = 0; mt < 4; ++mt)
#pragma unroll
                for (int g = 0; g < 4; ++g) {
                    float bv = bsum[l][g];
                    acc[mt][g] = (f32x4){bv, bv, bv, bv};
                }

            // input contribution
            if (l == 0)
                gemm_x(acc, &Xs[0][0][0], &Xs[1][0][0], Wih[0], col, q8, wv, lane);
            else
                gemm_h(acc, &Hs[0][l - 1][0][0], &Hs[1][l - 1][0][0], Wih[l], col, q8, wv, lane);
            // recurrent contribution
            gemm_h(acc, &Hs[0][l][0][0], &Hs[1][l][0][0], Whh[l], col, q8, wv, lane);

            __syncthreads();   // all reads of Hs[l] (and Hs[l-1]) complete

            // gates fully in-register; write new h (hi/lo) to LDS
#pragma unroll
            for (int mt = 0; mt < 4; ++mt) {
#pragma unroll
                for (int r = 0; r < 4; ++r) {
                    float zi = acc[mt][0][r];
                    float zf = acc[mt][1][r];
                    float zg = acc[mt][2][r];
                    float zo = acc[mt][3][r];
                    float ig = sigm(zi), fg = sigm(zf), og = sigm(zo), gg = tanh_(zg);
                    float cn = fg * cst[l][mt][r] + ig * gg;
                    cst[l][mt][r] = cn;
                    float h = og * tanh_(cn);
                    int m = mt * 16 + quad * 4 + r;
                    int j = wv * 16 + col;
                    _Float16 hh = (_Float16)h;
                    Hs[0][l][m][j] = hh;
                    Hs[1][l][m][j] = (_Float16)(h - (float)hh);
                }
            }
            __syncthreads();   // new h visible
        }

        // ---- head: out = h2 @ Wl^T + bl  (all 8 waves: mt = wv>>1, nt = wv&1) ----
        {
            const int mt = wv >> 1, nt = wv & 1;
            const _Float16* ah = &Hs[0][2][mt * 16 + col][0];
            const _Float16* al = &Hs[1][2][mt * 16 + col][0];
            f32x4 o = (f32x4){0, 0, 0, 0};
#pragma unroll
            for (int ks = 0; ks < 4; ++ks) {
                const _Float16* bt = wsp + W_HEAD + (nt * 4 + ks) * 1024 + lane * 8;
                f16x8 a_h = *(const f16x8*)(ah + ks * 32 + q8);
                f16x8 a_l = *(const f16x8*)(al + ks * 32 + q8);
                f16x8 b_h = *(const f16x8*)(bt);
                f16x8 b_l = *(const f16x8*)(bt + 512);
                o = __builtin_amdgcn_mfma_f32_16x16x32_f16(a_h, b_h, o, 0, 0, 0);
                o = __builtin_amdgcn_mfma_f32_16x16x32_f16(a_l, b_h, o, 0, 0, 0);
                o = __builtin_amdgcn_mfma_f32_16x16x32_f16(a_h, b_l, o, 0, 0, 0);
            }
            int i = nt * 16 + col;
            if (i < INW) {
#pragma unroll
                for (int r = 0; r < 4; ++r) {
                    int m = mt * 16 + quad * 4 + r;
                    out[(size_t)(b0 + m) * (TSTEPS * INW) + t * INW + i] = o[r] + blv;
                }
            }
        }
        __syncthreads();   // head reads of Hs[2] + Xs reuse fence before next t
    }
}

extern "C" void kernel_launch(void* const* d_in, const int* in_sizes, int n_in,
                              void* d_out, int out_size, void* d_ws, size_t ws_size,
                              hipStream_t stream) {
    const float* x    = (const float*)d_in[0];
    const float* Wih0 = (const float*)d_in[1];
    const float* Whh0 = (const float*)d_in[2];
    const float* bih0 = (const float*)d_in[3];
    const float* bhh0 = (const float*)d_in[4];
    const float* Wih1 = (const float*)d_in[5];
    const float* Whh1 = (const float*)d_in[6];
    const float* bih1 = (const float*)d_in[7];
    const float* bhh1 = (const float*)d_in[8];
    const float* Wih2 = (const float*)d_in[9];
    const float* Whh2 = (const float*)d_in[10];
    const float* bih2 = (const float*)d_in[11];
    const float* bhh2 = (const float*)d_in[12];
    const float* Wl   = (const float*)d_in[13];
    const float* bl   = (const float*)d_in[14];
    float* out = (float*)d_out;
    _Float16* ws = (_Float16*)d_ws;

    convert_w<<<(348160 + 255) / 256, 256, 0, stream>>>(Whh0, Whh1, Whh2, Wih1, Wih2, Wih0, Wl, ws);
    lstm_mfma<<<BATCH / NROW, THREADS, 0, stream>>>(
        x, bih0, bhh0, bih1, bhh1, bih2, bhh2, bl, ws, out);
}

// Round 5
// 911.169 us; speedup vs baseline: 5.2899x; 1.0002x over previous
//
#include <hip/hip_runtime.h>
#include <math.h>

#define BATCH  16384
#define TSTEPS 19
#define INW    17
#define HID    128
#define NROW   64          // batch rows per WG -> grid = 256 = 1 block/CU
#define THREADS 512        // 8 waves
#define KP     136         // padded row length (halfs) for h state (128+8)
#define KP0    40          // padded row length (halfs) for x (32+8)

typedef _Float16 f16x8 __attribute__((ext_vector_type(8)));
typedef float    f32x4 __attribute__((ext_vector_type(4)));

// ---- ws layout (halfs), MFMA-fragment-ordered tiles ----
// Big matrices (Whh0,Whh1,Whh2,Wih1,Wih2), each [512 rows][128 k]:
//   tile (n_tile 0..31, ks 0..3) = 1024 halfs: hi[512] | lo[512],
//   within plane: (quad*16 + col)*8 + j  -> lane*8 is coalesced.
#define W_BIG      0                 // 5 * 131072 = 655360
#define W_IH0      655360            // [512][32]: tile n_tile 0..31 = 1024 halfs (hi512|lo512)
#define W_HEAD     688128            // [32 rows][128]: (n_tile 0..1, ks 0..3) tiles of 1024
#define WS_HALFS   696320

__device__ __forceinline__ float fast_rcp(float x) { return __builtin_amdgcn_rcpf(x); }
__device__ __forceinline__ float sigm(float z)  { return fast_rcp(1.0f + __expf(-z)); }
__device__ __forceinline__ float tanh_(float z) { return 1.0f - 2.0f * fast_rcp(1.0f + __expf(2.0f * z)); }

// ---------------- weight conversion: fp32 -> f16 hi/lo, fragment order ----------------
__global__ void convert_w(const float* __restrict__ Whh0, const float* __restrict__ Whh1,
                          const float* __restrict__ Whh2, const float* __restrict__ Wih1,
                          const float* __restrict__ Wih2, const float* __restrict__ Wih0,
                          const float* __restrict__ Wl, _Float16* __restrict__ ws)
{
    int idx = blockIdx.x * 256 + threadIdx.x;
    if (idx < 327680) {
        int m = idx >> 16, e = idx & 65535;
        int r = e >> 7, k = e & 127;
        const float* src = (m == 0) ? Whh0 : (m == 1) ? Whh1 : (m == 2) ? Whh2
                          : (m == 3) ? Wih1 : Wih2;
        float v = src[e];
        _Float16 hi = (_Float16)v;
        int n_tile = r >> 4, colr = r & 15, ks = k >> 5, qd = (k >> 3) & 3, j = k & 7;
        int dst = W_BIG + m * 131072 + (n_tile * 4 + ks) * 1024 + (qd * 16 + colr) * 8 + j;
        ws[dst]       = hi;
        ws[dst + 512] = (_Float16)(v - (float)hi);
    } else if (idx < 344064) {
        int e = idx - 327680;              // [0, 16384)
        int r = e >> 5, k = e & 31;
        float v = (k < INW) ? Wih0[r * INW + k] : 0.0f;
        _Float16 hi = (_Float16)v;
        int n_tile = r >> 4, colr = r & 15, qd = k >> 3, j = k & 7;
        int dst = W_IH0 + n_tile * 1024 + (qd * 16 + colr) * 8 + j;
        ws[dst]       = hi;
        ws[dst + 512] = (_Float16)(v - (float)hi);
    } else if (idx < 348160) {
        int e = idx - 344064;              // [0, 4096)
        int r = e >> 7, k = e & 127;
        float v = (r < INW) ? Wl[(size_t)r * HID + k] : 0.0f;
        _Float16 hi = (_Float16)v;
        int n_tile = r >> 4, colr = r & 15, ks = k >> 5, qd = (k >> 3) & 3, j = k & 7;
        int dst = W_HEAD + (n_tile * 4 + ks) * 1024 + (qd * 16 + colr) * 8 + j;
        ws[dst]       = hi;
        ws[dst + 512] = (_Float16)(v - (float)hi);
    }
}

// ---------------- GEMM helpers ----------------
// acc[mt][g]: rows m = mt*16 + quad*4 + r, cols n = g*128 + wv*16 + col
// A from LDS h planes (hi/lo, row-major stride KP).
// B fragment tiles: coalesced, lane*8 offset within 512-half plane.
__device__ __forceinline__ void gemm_h(f32x4 acc[4][4],
                                       const _Float16* __restrict__ Ahi,
                                       const _Float16* __restrict__ Alo,
                                       const _Float16* __restrict__ B,
                                       int col, int q8, int wv, int lane)
{
    const _Float16* a_h = Ahi + col * KP;
    const _Float16* a_l = Alo + col * KP;
    const int l8 = lane * 8;
#pragma unroll
    for (int ks = 0; ks < 4; ++ks) {
        const int ko = ks * 32 + q8;
        f16x8 ah[4], al[4];
#pragma unroll
        for (int mt = 0; mt < 4; ++mt) {
            ah[mt] = *(const f16x8*)(a_h + mt * 16 * KP + ko);
            al[mt] = *(const f16x8*)(a_l + mt * 16 * KP + ko);
        }
#pragma unroll
        for (int g = 0; g < 4; ++g) {
            const _Float16* bt = B + ((g * 8 + wv) * 4 + ks) * 1024 + l8;
            f16x8 bh  = *(const f16x8*)(bt);
            f16x8 blo = *(const f16x8*)(bt + 512);
#pragma unroll
            for (int mt = 0; mt < 4; ++mt) {
                acc[mt][g] = __builtin_amdgcn_mfma_f32_16x16x32_f16(ah[mt], bh,  acc[mt][g], 0, 0, 0);
                acc[mt][g] = __builtin_amdgcn_mfma_f32_16x16x32_f16(al[mt], bh,  acc[mt][g], 0, 0, 0);
                acc[mt][g] = __builtin_amdgcn_mfma_f32_16x16x32_f16(ah[mt], blo, acc[mt][g], 0, 0, 0);
            }
        }
    }
}

// x-part for layer 0: K=32 (padded)
__device__ __forceinline__ void gemm_x(f32x4 acc[4][4],
                                       const _Float16* __restrict__ Xhi,
                                       const _Float16* __restrict__ Xlo,
                                       const _Float16* __restrict__ B,
                                       int col, int q8, int wv, int lane)
{
    const int l8 = lane * 8;
    f16x8 ah[4], al[4];
#pragma unroll
    for (int mt = 0; mt < 4; ++mt) {
        ah[mt] = *(const f16x8*)(Xhi + (mt * 16 + col) * KP0 + q8);
        al[mt] = *(const f16x8*)(Xlo + (mt * 16 + col) * KP0 + q8);
    }
#pragma unroll
    for (int g = 0; g < 4; ++g) {
        const _Float16* bt = B + (g * 8 + wv) * 1024 + l8;
        f16x8 bh  = *(const f16x8*)(bt);
        f16x8 blo = *(const f16x8*)(bt + 512);
#pragma unroll
        for (int mt = 0; mt < 4; ++mt) {
            acc[mt][g] = __builtin_amdgcn_mfma_f32_16x16x32_f16(ah[mt], bh,  acc[mt][g], 0, 0, 0);
            acc[mt][g] = __builtin_amdgcn_mfma_f32_16x16x32_f16(al[mt], bh,  acc[mt][g], 0, 0, 0);
            acc[mt][g] = __builtin_amdgcn_mfma_f32_16x16x32_f16(ah[mt], blo, acc[mt][g], 0, 0, 0);
        }
    }
}

// ---------------- main kernel ----------------
__global__ __launch_bounds__(THREADS, 1) void lstm_mfma(
    const float* __restrict__ x,
    const float* __restrict__ bih0, const float* __restrict__ bhh0,
    const float* __restrict__ bih1, const float* __restrict__ bhh1,
    const float* __restrict__ bih2, const float* __restrict__ bhh2,
    const float* __restrict__ bl,
    const _Float16* __restrict__ wsp,
    float* __restrict__ out)
{
    __shared__ _Float16 Hs[2][3][NROW][KP];   // [hi/lo][layer][m][k]  = 104448 B
    __shared__ _Float16 Xs[2][NROW][KP0];     // [hi/lo][m][k]         = 10240 B

    const int tid  = threadIdx.x;
    const int wv   = tid >> 6;
    const int lane = tid & 63;
    const int col  = lane & 15;
    const int quad = lane >> 4;
    const int q8   = quad * 8;
    const int b0   = blockIdx.x * NROW;

    // bias sums in registers: bsum[l][g] for n = g*128 + wv*16 + col
    const float* bihA[3] = {bih0, bih1, bih2};
    const float* bhhA[3] = {bhh0, bhh1, bhh2};
    float bsum[3][4];
#pragma unroll
    for (int l = 0; l < 3; ++l)
#pragma unroll
        for (int g = 0; g < 4; ++g) {
            int n = g * 128 + wv * 16 + col;
            bsum[l][g] = bihA[l][n] + bhhA[l][n];
        }

    // zero h state (hi+lo planes): 104448 B = 26112 floats
    for (int i = tid; i < 26112; i += THREADS) ((float*)Hs)[i] = 0.0f;

    f32x4 cst[3][4];
#pragma unroll
    for (int l = 0; l < 3; ++l)
#pragma unroll
        for (int mt = 0; mt < 4; ++mt) cst[l][mt] = (f32x4){0, 0, 0, 0};

    // weight pointers (fragment-ordered)
    const _Float16* Whh[3] = {wsp + W_BIG,  wsp + W_BIG + 131072, wsp + W_BIG + 262144};
    const _Float16* Wih[3] = {wsp + W_IH0, wsp + W_BIG + 393216, wsp + W_BIG + 524288};

    // head bias
    float blv = 0.0f;
    {
        int i = (wv & 1) * 16 + col;
        if (i < INW) blv = bl[i];
    }

    __syncthreads();

#pragma unroll 1
    for (int t = 0; t < TSTEPS; ++t) {
        // ---- stage x[:, t, :] as f16 hi/lo (K padded to 32) ----
        for (int ii = tid; ii < NROW * 32; ii += THREADS) {
            int m = ii >> 5, k = ii & 31;
            float v = (k < INW) ? x[(size_t)(b0 + m) * (TSTEPS * INW) + t * INW + k] : 0.0f;
            _Float16 hi = (_Float16)v;
            Xs[0][m][k] = hi;
            Xs[1][m][k] = (_Float16)(v - (float)hi);
        }
        __syncthreads();

#pragma unroll 1
        for (int l = 0; l < 3; ++l) {
            f32x4 acc[4][4];
#pragma unroll
            for (int mt = 0; mt < 4; ++mt)
#pragma unroll
                for (int g = 0; g < 4; ++g) {
                    float bv = bsum[l][g];
                    acc[mt][g] = (f32x4){bv, bv, bv, bv};
                }

            // input contribution
            if (l == 0)
                gemm_x(acc, &Xs[0][0][0], &Xs[1][0][0], Wih[0], col, q8, wv, lane);
            else
                gemm_h(acc, &Hs[0][l - 1][0][0], &Hs[1][l - 1][0][0], Wih[l], col, q8, wv, lane);
            // recurrent contribution
            gemm_h(acc, &Hs[0][l][0][0], &Hs[1][l][0][0], Whh[l], col, q8, wv, lane);

            __syncthreads();   // all reads of Hs[l] (and Hs[l-1]) complete

            // gates fully in-register; write new h (hi/lo) to LDS
#pragma unroll
            for (int mt = 0; mt < 4; ++mt) {
#pragma unroll
                for (int r = 0; r < 4; ++r) {
                    float zi = acc[mt][0][r];
                    float zf = acc[mt][1][r];
                    float zg = acc[mt][2][r];
                    float zo = acc[mt][3][r];
                    float ig = sigm(zi), fg = sigm(zf), og = sigm(zo), gg = tanh_(zg);
                    float cn = fg * cst[l][mt][r] + ig * gg;
                    cst[l][mt][r] = cn;
                    float h = og * tanh_(cn);
                    int m = mt * 16 + quad * 4 + r;
                    int j = wv * 16 + col;
                    _Float16 hh = (_Float16)h;
                    Hs[0][l][m][j] = hh;
                    Hs[1][l][m][j] = (_Float16)(h - (float)hh);
                }
            }
            __syncthreads();   // new h visible
        }

        // ---- head: out = h2 @ Wl^T + bl  (all 8 waves: mt = wv>>1, nt = wv&1) ----
        {
            const int mt = wv >> 1, nt = wv & 1;
            const _Float16* ah = &Hs[0][2][mt * 16 + col][0];
            const _Float16* al = &Hs[1][2][mt * 16 + col][0];
            f32x4 o = (f32x4){0, 0, 0, 0};
#pragma unroll
            for (int ks = 0; ks < 4; ++ks) {
                const _Float16* bt = wsp + W_HEAD + (nt * 4 + ks) * 1024 + lane * 8;
                f16x8 a_h = *(const f16x8*)(ah + ks * 32 + q8);
                f16x8 a_l = *(const f16x8*)(al + ks * 32 + q8);
                f16x8 b_h = *(const f16x8*)(bt);
                f16x8 b_l = *(const f16x8*)(bt + 512);
                o = __builtin_amdgcn_mfma_f32_16x16x32_f16(a_h, b_h, o, 0, 0, 0);
                o = __builtin_amdgcn_mfma_f32_16x16x32_f16(a_l, b_h, o, 0, 0, 0);
                o = __builtin_amdgcn_mfma_f32_16x16x32_f16(a_h, b_l, o, 0, 0, 0);
            }
            int i = nt * 16 + col;
            if (i < INW) {
#pragma unroll
                for (int r = 0; r < 4; ++r) {
                    int m = mt * 16 + quad * 4 + r;
                    out[(size_t)(b0 + m) * (TSTEPS * INW) + t * INW + i] = o[r] + blv;
                }
            }
        }
        __syncthreads();   // head reads of Hs[2] + Xs reuse fence before next t
    }
}

extern "C" void kernel_launch(void* const* d_in, const int* in_sizes, int n_in,
                              void* d_out, int out_size, void* d_ws, size_t ws_size,
                              hipStream_t stream) {
    const float* x    = (const float*)d_in[0];
    const float* Wih0 = (const float*)d_in[1];
    const float* Whh0 = (const float*)d_in[2];
    const float* bih0 = (const float*)d_in[3];
    const float* bhh0 = (const float*)d_in[4];
    const float* Wih1 = (const float*)d_in[5];
    const float* Whh1 = (const float*)d_in[6];
    const float* bih1 = (const float*)d_in[7];
    const float* bhh1 = (const float*)d_in[8];
    const float* Wih2 = (const float*)d_in[9];
    const float* Whh2 = (const float*)d_in[10];
    const float* bih2 = (const float*)d_in[11];
    const float* bhh2 = (const float*)d_in[12];
    const float* Wl   = (const float*)d_in[13];
    const float* bl   = (const float*)d_in[14];
    float* out = (float*)d_out;
    _Float16* ws = (_Float16*)d_ws;

    convert_w<<<(348160 + 255) / 256, 256, 0, stream>>>(Whh0, Whh1, Whh2, Wih1, Wih2, Wih0, Wl, ws);
    lstm_mfma<<<BATCH / NROW, THREADS, 0, stream>>>(
        x, bih0, bhh0, bih1, bhh1, bih2, bhh2, bl, ws, out);
}